// Round 13
// baseline (100.735 us; speedup 1.0000x reference)
//
#include <hip/hip_runtime.h>

#define CROP_H 14
#define CROP_W 14
#define IMG_B 8
#define IMG_C 256
#define IMG_H 100
#define IMG_W 152
#define NBOX 1000
#define PLANE (IMG_H * IMG_W)                 // 15200
#define ZOFF  PLANE                           // zero-region base in LDS plane
#define POS (CROP_H * CROP_W)                 // 196
#define PAIRS (POS / 2)                       // 98 x-pair tasks per box
#define OUT_PER_BOX (IMG_C * POS)             // 50176
#define BOXCAP 16                             // boxes per chunk
#define CG 32                                 // fallback path
#define NCG (IMG_C / CG)

typedef float f2u __attribute__((ext_vector_type(2), aligned(8)));
typedef float f4u __attribute__((ext_vector_type(4), aligned(16)));

// workspace layout (bytes)
#define WS_ROWG   0                            // 1000*14*8   = 112000
#define WS_COLG   112000                       // 1000*7*16   = 112000
#define WS_OBOX   224000                       // 1000*4      = 4000
#define WS_PERM   228000                       // 1000*4      = 4000
#define WS_OFFS   232000                       // 9*4         = 36
#define WS_NEED   232036

// ---------------------------------------------------------------------------
// Kernel A: stable counting-sort of boxes by box_ind -> perm + per-image
// offsets. Deterministic (atomicOr order-independent, popcount ranks).
// ---------------------------------------------------------------------------
__global__ __launch_bounds__(1024) void sort_boxes_kernel(
    const int* __restrict__ box_ind,
    int* __restrict__ perm,
    int* __restrict__ offsets)            // [IMG_B + 1]
{
    __shared__ unsigned s_mask[IMG_B][32];
    __shared__ int s_tot[IMG_B];
    const int tid = threadIdx.x;

    if (tid < IMG_B * 32) ((unsigned*)s_mask)[tid] = 0u;
    __syncthreads();

    int key = 0;
    if (tid < NBOX) {
        key = box_ind[tid];
        atomicOr(&s_mask[key][tid >> 5], 1u << (tid & 31));
    }
    __syncthreads();

    if (tid < IMG_B) {
        int t = 0;
        #pragma unroll
        for (int w = 0; w < 32; ++w) t += __popc(s_mask[tid][w]);
        s_tot[tid] = t;
    }
    __syncthreads();

    if (tid == 0) {
        int acc = 0;
        #pragma unroll
        for (int k = 0; k < IMG_B; ++k) { offsets[k] = acc; acc += s_tot[k]; }
        offsets[IMG_B] = acc;
    }

    if (tid < NBOX) {
        int base = 0;
        #pragma unroll
        for (int k = 0; k < IMG_B; ++k) base += (k < key) ? s_tot[k] : 0;
        const int w = tid >> 5, b = tid & 31;
        int r = __popc(s_mask[key][w] & ((b == 0) ? 0u : ((1u << b) - 1u)));
        for (int ww = 0; ww < w; ++ww) r += __popc(s_mask[key][ww]);
        perm[base + r] = tid;
    }
}

// ---------------------------------------------------------------------------
// Kernel P: precompute interpolation packs in SORTED order.
//  rowG[s*14+y] = {int rb (r0*152, or ZOFF if row invalid), yw'}
//  colG[s*7+xg] = {int cb0, xw0', int cb1, xw1'}  (cb=ZOFF if col invalid)
//  clamp-by-weight: bottom/right clamp -> weight 1.0 (generic lerp lands on
//  the clamped texel, <=1 ulp); validity-by-address: ZOFF reads zeros.
// ---------------------------------------------------------------------------
__global__ __launch_bounds__(64) void build_packs_kernel(
    const float* __restrict__ boxes,
    const int* __restrict__ perm,
    f2u* __restrict__ rowG,
    f4u* __restrict__ colG,
    unsigned* __restrict__ oboxG)
{
    const int s = blockIdx.x;              // sorted position 0..999
    const int t = threadIdx.x;
    if (t >= 22) return;
    const int n = perm[s];

    if (t == 21) { oboxG[s] = (unsigned)(n * OUT_PER_BOX); return; }

    const float y1 = boxes[n * 4 + 0];
    const float x1 = boxes[n * 4 + 1];
    const float y2 = boxes[n * 4 + 2];
    const float x2 = boxes[n * 4 + 3];

    if (t < CROP_H) {
        // exact fp32 RN, no FMA — must match numpy bitwise (validity is a
        // discontinuous function of in_y)
        const float hs   = __fdiv_rn(__fmul_rn(__fsub_rn(y2, y1), (float)(IMG_H - 1)),
                                     (float)(CROP_H - 1));
        const float in_y = __fadd_rn(__fmul_rn(y1, (float)(IMG_H - 1)),
                                     __fmul_rn((float)t, hs));
        const int vy = (in_y >= 0.0f) && (in_y <= (float)(IMG_H - 1));
        const float top = floorf(in_y);
        const float yw  = __fsub_rn(in_y, top);
        const int ti = (int)fminf(fmaxf(top, 0.0f), (float)(IMG_H - 1));
        const int r0 = min(ti, IMG_H - 2);
        const bool sely = (ti == IMG_H - 1);
        f2u e;
        e.x = __int_as_float(vy ? (r0 * IMG_W) : ZOFF);
        e.y = sely ? 1.0f : yw;
        rowG[s * CROP_H + t] = e;
    } else {
        const int xg = t - CROP_H;         // 0..6
        const float ws = __fdiv_rn(__fmul_rn(__fsub_rn(x2, x1), (float)(IMG_W - 1)),
                                   (float)(CROP_W - 1));
        const float x1W = __fmul_rn(x1, (float)(IMG_W - 1));
        f4u e;
        #pragma unroll
        for (int k = 0; k < 2; ++k) {
            const int x = 2 * xg + k;
            const float in_x = __fadd_rn(x1W, __fmul_rn((float)x, ws));
            const int vx = (in_x >= 0.0f) && (in_x <= (float)(IMG_W - 1));
            const float left = floorf(in_x);
            const float xw   = __fsub_rn(in_x, left);
            const int li = (int)fminf(fmaxf(left, 0.0f), (float)(IMG_W - 1));
            const int c0 = min(li, IMG_W - 2);
            const bool selx = (li == IMG_W - 1);
            const int   cb  = vx ? c0 : ZOFF;
            const float xwp = selx ? 1.0f : xw;
            if (k == 0) { e.x = __int_as_float(cb); e.y = xwp; }
            else        { e.z = __int_as_float(cb); e.w = xwp; }
        }
        colG[s * 7 + xg] = e;
    }
}

// ---------------------------------------------------------------------------
// Kernel B: plane-in-LDS crop-and-resize, minimal hot loop.
// Thread invariants: slot = tid>>6, r = tid&63 (+64); y = r*9363>>16 (exact
// /7 for r<98), xg = r - 7y; out offset = 2*r. Per chunk: coalesced pack
// COPY (no math) -> barrier -> <=2 pair-tasks/thread -> barrier.
// Per pair-task: 1 ds_read_b64 + 1 ds_read_b128 + 4 ds_read2_b32 + ~14 VALU
// + 1 float2 store. 65 KB LDS -> 2 blocks/CU (32 waves).
// ---------------------------------------------------------------------------
__global__ __launch_bounds__(1024, 8) void CropAndResize_16630113370849_kernel(
    const float* __restrict__ image,
    const f2u* __restrict__ rowG,
    const f4u* __restrict__ colG,
    const unsigned* __restrict__ oboxG,
    const int* __restrict__ offsets,
    float* __restrict__ out)
{
    __shared__ __align__(16) float s_plane[15360];   // 15200 + 160 zeros
    __shared__ f2u s_row[BOXCAP * CROP_H];           // 224 entries
    __shared__ f4u s_colp[BOXCAP * 7];               // 112 entries
    __shared__ unsigned s_obox[BOXCAP];

    const int c   = blockIdx.x;              // channel 0..255
    const int b   = blockIdx.y;              // image 0..7
    const int tid = threadIdx.x;

    // stage plane (3800 float4, coalesced) + zero region
    {
        const float4* __restrict__ src =
            (const float4*)(image + ((size_t)b * IMG_C + c) * PLANE);
        float4* dst = (float4*)s_plane;
        #pragma unroll
        for (int i = 0; i < 4; ++i) {
            const int e = i * 1024 + tid;
            if (e < PLANE / 4) dst[e] = src[e];
        }
        if (tid < 160) s_plane[ZOFF + tid] = 0.0f;
    }

    // per-thread loop-invariant task geometry
    const int slot = tid >> 6;               // 0..15
    const int r0   = tid & 63;               // task ids r0 and r0+64
    const int r1   = r0 + 64;                // < 98 check below
    const int y0   = (r0 * 9363) >> 16;      // exact r/7 for r<98
    const int xg0  = r0 - y0 * 7;
    const int y1i  = (r1 * 9363) >> 16;
    const int xg1  = r1 - y1i * 7;
    const bool has1 = (r1 < PAIRS);

    const int s0 = offsets[b], nb = offsets[b + 1] - s0;
    const unsigned cPOS = (unsigned)(c * POS);

    for (int ckb = 0; ckb < nb; ckb += BOXCAP) {
        const int base = s0 + ckb;
        const int cnt  = min(BOXCAP, nb - ckb);

        __syncthreads();   // plane ready (1st) / prev chunk readers done

        // pack copy: rows [0,cnt*14), cols [256,256+cnt*7), obox [384,384+cnt)
        if (tid < cnt * CROP_H) {
            s_row[tid] = rowG[base * CROP_H + tid];
        } else if (tid >= 256 && tid < 256 + cnt * 7) {
            s_colp[tid - 256] = colG[base * 7 + (tid - 256)];
        } else if (tid >= 384 && tid < 384 + cnt) {
            s_obox[tid - 384] = oboxG[base + tid - 384];
        }
        __syncthreads();

        if (slot < cnt) {
            const unsigned obase = s_obox[slot] + cPOS;
            float* __restrict__ po = out + (size_t)obase;

            // ---- task 0 (r0) ----
            {
                const f2u re = s_row[slot * CROP_H + y0];
                const f4u ce = s_colp[slot * 7 + xg0];
                const int   rb  = __float_as_int(re.x);
                const float yw  = re.y;
                const int off0 = min(rb + __float_as_int(ce.x), ZOFF);
                const int off1 = min(rb + __float_as_int(ce.z), ZOFF);
                const float xw0 = ce.y, xw1 = ce.w;

                const float* p0 = s_plane + off0;
                const float* p1 = s_plane + off1;
                const float a0 = p0[0], a1 = p0[1];
                const float b0 = p0[IMG_W], b1 = p0[IMG_W + 1];
                const float c0_ = p1[0], c1_ = p1[1];
                const float d0_ = p1[IMG_W], d1_ = p1[IMG_W + 1];

                const float t0 = a0 + (a1 - a0) * xw0;
                const float u0 = b0 + (b1 - b0) * xw0;
                const float t1 = c0_ + (c1_ - c0_) * xw1;
                const float u1 = d0_ + (d1_ - d0_) * xw1;
                f2u res;
                res.x = t0 + (u0 - t0) * yw;
                res.y = t1 + (u1 - t1) * yw;
                *(f2u*)(po + 2 * r0) = res;
            }
            // ---- task 1 (r0+64) ----
            if (has1) {
                const f2u re = s_row[slot * CROP_H + y1i];
                const f4u ce = s_colp[slot * 7 + xg1];
                const int   rb  = __float_as_int(re.x);
                const float yw  = re.y;
                const int off0 = min(rb + __float_as_int(ce.x), ZOFF);
                const int off1 = min(rb + __float_as_int(ce.z), ZOFF);
                const float xw0 = ce.y, xw1 = ce.w;

                const float* p0 = s_plane + off0;
                const float* p1 = s_plane + off1;
                const float a0 = p0[0], a1 = p0[1];
                const float b0 = p0[IMG_W], b1 = p0[IMG_W + 1];
                const float c0_ = p1[0], c1_ = p1[1];
                const float d0_ = p1[IMG_W], d1_ = p1[IMG_W + 1];

                const float t0 = a0 + (a1 - a0) * xw0;
                const float u0 = b0 + (b1 - b0) * xw0;
                const float t1 = c0_ + (c1_ - c0_) * xw1;
                const float u1 = d0_ + (d1_ - d0_) * xw1;
                f2u res;
                res.x = t0 + (u0 - t0) * yw;
                res.y = t1 + (u1 - t1) * yw;
                *(f2u*)(po + 2 * r1) = res;
            }
        }
    }
}

// ---------------------------------------------------------------------------
// Fallback (R5 structure, known 104 us) if workspace is too small.
// ---------------------------------------------------------------------------
__global__ __launch_bounds__(256) void crop_chw_kernel(
    const float* __restrict__ image,
    const float* __restrict__ boxes,
    const int* __restrict__ box_ind,
    float* __restrict__ out)
{
    const int bid  = blockIdx.x;
    const int cg   = bid & 7;
    const int n    = bid >> 3;
    const int tid  = threadIdx.x;
    if (tid >= POS) return;

    const int b = box_ind[n];
    const int y = tid / CROP_W;
    const int x = tid - y * CROP_W;

    const float y1 = boxes[n * 4 + 0];
    const float x1 = boxes[n * 4 + 1];
    const float y2 = boxes[n * 4 + 2];
    const float x2 = boxes[n * 4 + 3];

    const float hs   = __fdiv_rn(__fmul_rn(__fsub_rn(y2, y1), (float)(IMG_H - 1)),
                                 (float)(CROP_H - 1));
    const float in_y = __fadd_rn(__fmul_rn(y1, (float)(IMG_H - 1)),
                                 __fmul_rn((float)y, hs));
    const int vy = (in_y >= 0.0f) && (in_y <= (float)(IMG_H - 1));
    const float top = floorf(in_y);
    const float yw  = __fsub_rn(in_y, top);
    const int ti = (int)fminf(fmaxf(top, 0.0f), (float)(IMG_H - 1));

    const float ws   = __fdiv_rn(__fmul_rn(__fsub_rn(x2, x1), (float)(IMG_W - 1)),
                                 (float)(CROP_W - 1));
    const float in_x = __fadd_rn(__fmul_rn(x1, (float)(IMG_W - 1)),
                                 __fmul_rn((float)x, ws));
    const int vx = (in_x >= 0.0f) && (in_x <= (float)(IMG_W - 1));
    const float left = floorf(in_x);
    const float xw   = __fsub_rn(in_x, left);
    const int li = (int)fminf(fmaxf(left, 0.0f), (float)(IMG_W - 1));

    const int r0 = min(ti, IMG_H - 2);
    const int c0 = min(li, IMG_W - 2);
    const bool sely = (ti == IMG_H - 1);
    const bool selx = (li == IMG_W - 1);
    const bool vald = (vy & vx) != 0;

    const float* __restrict__ pl =
        image + (size_t)b * (size_t)(IMG_C * PLANE)
              + (size_t)(cg * CG) * PLANE + (r0 * IMG_W + c0);
    float* __restrict__ po =
        out + (size_t)n * (size_t)OUT_PER_BOX + (size_t)(cg * CG) * POS + tid;

    #pragma unroll 8
    for (int cl = 0; cl < CG; ++cl) {
        const float2 ra = *(const float2*)(pl);
        const float2 rb = *(const float2*)(pl + IMG_W);
        const float tA = sely ? rb.x : ra.x;
        const float tB = sely ? rb.y : ra.y;
        const float tl = selx ? tB : tA;
        const float bl = selx ? rb.y : rb.x;
        const float top_v = __fadd_rn(tl, __fmul_rn(__fsub_rn(tB, tl), xw));
        const float bot_v = __fadd_rn(bl, __fmul_rn(__fsub_rn(rb.y, bl), xw));
        const float v = __fadd_rn(top_v, __fmul_rn(__fsub_rn(bot_v, top_v), yw));
        *po = vald ? v : 0.0f;
        pl += PLANE;
        po += POS;
    }
}

extern "C" void kernel_launch(void* const* d_in, const int* in_sizes, int n_in,
                              void* d_out, int out_size, void* d_ws, size_t ws_size,
                              hipStream_t stream) {
    const float* image  = (const float*)d_in[0];
    const float* boxes  = (const float*)d_in[1];
    const int*   boxind = (const int*)d_in[2];
    float* out = (float*)d_out;

    if (ws_size >= (size_t)WS_NEED) {
        char* ws = (char*)d_ws;
        f2u*      rowG    = (f2u*)(ws + WS_ROWG);
        f4u*      colG    = (f4u*)(ws + WS_COLG);
        unsigned* oboxG   = (unsigned*)(ws + WS_OBOX);
        int*      perm    = (int*)(ws + WS_PERM);
        int*      offsets = (int*)(ws + WS_OFFS);

        sort_boxes_kernel<<<1, 1024, 0, stream>>>(boxind, perm, offsets);
        build_packs_kernel<<<NBOX, 64, 0, stream>>>(boxes, perm, rowG, colG, oboxG);
        CropAndResize_16630113370849_kernel<<<dim3(IMG_C, IMG_B), 1024, 0, stream>>>(
            image, rowG, colG, oboxG, offsets, out);
    } else {
        crop_chw_kernel<<<dim3(NBOX * NCG), 256, 0, stream>>>(
            image, boxes, boxind, out);
    }
}